// Round 1
// baseline (5221.181 us; speedup 1.0000x reference)
//
#include <hip/hip_runtime.h>
#include <math.h>

#define HH 128
#define WW 128
#define BB 4
#define HWSZ (HH*WW)

__device__ __forceinline__ float lrelu_f(float v) { return v >= 0.0f ? v : 0.1f * v; }

// ---------------------------------------------------------------------------
// conv1: 130 input channels gathered from [x_flow_warped(64) | x_current(64) | flow(2)]
// 3x3 SAME conv + leaky relu. Tile 16x16, OCPT=16 output channels per thread.
// ---------------------------------------------------------------------------
template<int CICHUNK, int OCPT>
__global__ __launch_bounds__(256)
void conv1_k(const float* __restrict__ xfw, const float* __restrict__ xc,
             const float* __restrict__ flow, const float* __restrict__ wgt,
             const float* __restrict__ bias, float* __restrict__ out)
{
    constexpr int CIN = 130;
    const int tid = threadIdx.x;
    const int tx = tid & 15, ty = tid >> 4;
    const int bz = blockIdx.z;          // b*4 + ocg   (64/16 = 4 oc groups)
    const int b   = bz >> 2;
    const int ocBase = (bz & 3) * OCPT;
    const int x0t = blockIdx.x * 16, y0t = blockIdx.y * 16;
    const int px = x0t + tx, py = y0t + ty;

    __shared__ float s_in[CICHUNK][18][18];
    __shared__ __align__(16) float s_w[CICHUNK][OCPT][12];

    float acc[OCPT];
#pragma unroll
    for (int o = 0; o < OCPT; ++o) acc[o] = 0.0f;

    for (int cc = 0; cc < CIN; cc += CICHUNK) {     // 13 chunks of 10
        __syncthreads();
        for (int idx = tid; idx < CICHUNK * 324; idx += 256) {
            int c = idx / 324; int r = idx - c * 324;
            int iy = r / 18;   int ix = r - iy * 18;
            int gy = y0t + iy - 1, gx = x0t + ix - 1;
            float v = 0.0f;
            if (gy >= 0 && gy < HH && gx >= 0 && gx < WW) {
                int ci = cc + c;
                if (ci < 64)        v = xfw[((size_t)(b*64 + ci)      * HH + gy) * WW + gx];
                else if (ci < 128)  v = xc [((size_t)(b*64 + ci - 64) * HH + gy) * WW + gx];
                else                v = flow[((size_t)(b*2 + ci - 128)* HH + gy) * WW + gx];
            }
            s_in[c][iy][ix] = v;
        }
        for (int idx = tid; idx < CICHUNK * OCPT * 9; idx += 256) {
            int c = idx / (OCPT * 9); int r = idx - c * (OCPT * 9);
            int o = r / 9; int k = r - o * 9;
            s_w[c][o][k] = wgt[((size_t)(ocBase + o) * CIN + cc + c) * 9 + k];
        }
        __syncthreads();
#pragma unroll
        for (int c = 0; c < CICHUNK; ++c) {
            float t[9];
#pragma unroll
            for (int dy = 0; dy < 3; ++dy)
#pragma unroll
                for (int dx = 0; dx < 3; ++dx)
                    t[dy*3+dx] = s_in[c][ty+dy][tx+dx];
#pragma unroll
            for (int o = 0; o < OCPT; ++o) {
                const float* wr = &s_w[c][o][0];
#pragma unroll
                for (int k = 0; k < 9; ++k)
                    acc[o] = fmaf(t[k], wr[k], acc[o]);
            }
        }
    }

#pragma unroll
    for (int o = 0; o < OCPT; ++o) {
        int oc = ocBase + o;
        float v = lrelu_f(acc[o] + bias[oc]);
        out[((size_t)(b*64 + oc) * HH + py) * WW + px] = v;
    }
}

// ---------------------------------------------------------------------------
// generic 64-in-channel 3x3 SAME conv.  EPI 0 = leaky relu (conv2/conv3),
// EPI 1 = DCN offset/mask transform (conv4): ch<288 -> 10*tanh(v)+flow_yx,
// ch>=288 -> sigmoid(v).
// ---------------------------------------------------------------------------
template<int CICHUNK, int OCPT, int EPI>
__global__ __launch_bounds__(256)
void conv64_k(const float* __restrict__ in, const float* __restrict__ wgt,
              const float* __restrict__ bias, float* __restrict__ out,
              int ocgCount, int OC, const float* __restrict__ flow)
{
    constexpr int CIN = 64;
    const int tid = threadIdx.x;
    const int tx = tid & 15, ty = tid >> 4;
    const int bz = blockIdx.z;
    const int b   = bz / ocgCount;
    const int ocg = bz - b * ocgCount;
    const int ocBase = ocg * OCPT;
    const int x0t = blockIdx.x * 16, y0t = blockIdx.y * 16;
    const int px = x0t + tx, py = y0t + ty;

    __shared__ float s_in[CICHUNK][18][18];
    __shared__ __align__(16) float s_w[CICHUNK][OCPT][12];

    float acc[OCPT];
#pragma unroll
    for (int o = 0; o < OCPT; ++o) acc[o] = 0.0f;

    for (int cc = 0; cc < CIN; cc += CICHUNK) {
        __syncthreads();
        for (int idx = tid; idx < CICHUNK * 324; idx += 256) {
            int c = idx / 324; int r = idx - c * 324;
            int iy = r / 18;   int ix = r - iy * 18;
            int gy = y0t + iy - 1, gx = x0t + ix - 1;
            float v = 0.0f;
            if (gy >= 0 && gy < HH && gx >= 0 && gx < WW)
                v = in[((size_t)(b*CIN + cc + c) * HH + gy) * WW + gx];
            s_in[c][iy][ix] = v;
        }
        for (int idx = tid; idx < CICHUNK * OCPT * 9; idx += 256) {
            int c = idx / (OCPT * 9); int r = idx - c * (OCPT * 9);
            int o = r / 9; int k = r - o * 9;
            s_w[c][o][k] = wgt[((size_t)(ocBase + o) * CIN + cc + c) * 9 + k];
        }
        __syncthreads();
#pragma unroll
        for (int c = 0; c < CICHUNK; ++c) {
            float t[9];
#pragma unroll
            for (int dy = 0; dy < 3; ++dy)
#pragma unroll
                for (int dx = 0; dx < 3; ++dx)
                    t[dy*3+dx] = s_in[c][ty+dy][tx+dx];
#pragma unroll
            for (int o = 0; o < OCPT; ++o) {
                const float* wr = &s_w[c][o][0];
#pragma unroll
                for (int k = 0; k < 9; ++k)
                    acc[o] = fmaf(t[k], wr[k], acc[o]);
            }
        }
    }

#pragma unroll
    for (int o = 0; o < OCPT; ++o) {
        int oc = ocBase + o;
        float v = acc[o] + bias[oc];
        if (EPI == 0) {
            v = lrelu_f(v);
        } else {
            if (oc < 288) {
                // offset channel: even -> +flow ch1, odd -> +flow ch0 (flow_yx tile)
                float fl = flow[((size_t)(b*2 + ((oc & 1) ^ 1)) * HH + py) * WW + px];
                v = 10.0f * tanhf(v) + fl;
            } else {
                v = 1.0f / (1.0f + expf(-v));   // sigmoid mask
            }
        }
        out[((size_t)(b*OC + oc) * HH + py) * WW + px] = v;
    }
}

// ---------------------------------------------------------------------------
// deformable conv: 16 deform groups, Cg=4, K=9, bilinear sampling with zero
// padding.  Block = 16x16 pixels, each thread accumulates 32 output channels
// (2 oc-groups in grid.z for occupancy).
// ---------------------------------------------------------------------------
__global__ __launch_bounds__(256)
void dcn_k(const float* __restrict__ x, const float* __restrict__ o4,
           const float* __restrict__ wgt, const float* __restrict__ bias,
           float* __restrict__ out)
{
    const int tid = threadIdx.x;
    const int tx = tid & 15, ty = tid >> 4;
    const int bz = blockIdx.z;          // b*2 + ocg
    const int b = bz >> 1;
    const int ocBase = (bz & 1) * 32;
    const int px = blockIdx.x * 16 + tx, py = blockIdx.y * 16 + ty;
    const int pix = py * WW + px;

    __shared__ __align__(16) float s_w[32][9][4];   // [oc][k][cg]

    float acc[32];
#pragma unroll
    for (int o = 0; o < 32; ++o) acc[o] = 0.0f;

    const float* offp = o4 + (size_t)b * 432 * HWSZ;
    const float* xb   = x  + (size_t)b * 64  * HWSZ;

    for (int dg = 0; dg < 16; ++dg) {
        __syncthreads();
        for (int idx = tid; idx < 32 * 36; idx += 256) {
            int o = idx / 36; int r = idx - o * 36;
            int k = r >> 2; int cg = r & 3;
            s_w[o][k][cg] = wgt[((size_t)(ocBase + o) * 64 + dg*4 + cg) * 9 + k];
        }
        __syncthreads();
#pragma unroll
        for (int k = 0; k < 9; ++k) {
            int ch2 = (dg * 9 + k) * 2;
            float oy = offp[(size_t)ch2       * HWSZ + pix];
            float ox = offp[(size_t)(ch2 + 1) * HWSZ + pix];
            float m  = offp[(size_t)(288 + dg*9 + k) * HWSZ + pix];
            float ys = (float)py + (float)(k / 3 - 1) + oy;
            float xs = (float)px + (float)(k % 3 - 1) + ox;
            float y0f = floorf(ys), x0f = floorf(xs);
            float wy = ys - y0f,    wx = xs - x0f;
            int y0 = (int)y0f, x0i = (int)x0f;
            int y1 = y0 + 1,   x1  = x0i + 1;
            float fy0 = (y0 >= 0 && y0 < HH) ? 1.0f : 0.0f;
            float fy1 = (y1 >= 0 && y1 < HH) ? 1.0f : 0.0f;
            float fx0 = (x0i >= 0 && x0i < WW) ? 1.0f : 0.0f;
            float fx1 = (x1 >= 0 && x1 < WW) ? 1.0f : 0.0f;
            int yc0 = min(max(y0, 0), HH-1), yc1 = min(max(y1, 0), HH-1);
            int xc0 = min(max(x0i,0), WW-1), xc1 = min(max(x1, 0), WW-1);
            float f00 = fy0 * fx0, f01 = fy0 * fx1, f10 = fy1 * fx0, f11 = fy1 * fx1;
            float sv[4];
#pragma unroll
            for (int cg = 0; cg < 4; ++cg) {
                const float* xp = xb + (size_t)(dg*4 + cg) * HWSZ;
                float v00 = xp[yc0 * WW + xc0] * f00;
                float v01 = xp[yc0 * WW + xc1] * f01;
                float v10 = xp[yc1 * WW + xc0] * f10;
                float v11 = xp[yc1 * WW + xc1] * f11;
                float top = v00 * (1.0f - wx) + v01 * wx;
                float bot = v10 * (1.0f - wx) + v11 * wx;
                sv[cg] = (top * (1.0f - wy) + bot * wy) * m;
            }
#pragma unroll
            for (int o = 0; o < 32; ++o) {
                const float4 wv = *(const float4*)&s_w[o][k][0];
                acc[o] = fmaf(sv[0], wv.x,
                          fmaf(sv[1], wv.y,
                           fmaf(sv[2], wv.z,
                            fmaf(sv[3], wv.w, acc[o]))));
            }
        }
    }

#pragma unroll
    for (int o = 0; o < 32; ++o) {
        int oc = ocBase + o;
        out[(size_t)(b*64 + oc) * HWSZ + pix] = acc[o] + bias[oc];
    }
}

// ---------------------------------------------------------------------------
extern "C" void kernel_launch(void* const* d_in, const int* in_sizes, int n_in,
                              void* d_out, int out_size, void* d_ws, size_t ws_size,
                              hipStream_t stream)
{
    const float* x    = (const float*)d_in[0];
    const float* xfw  = (const float*)d_in[1];
    const float* xc   = (const float*)d_in[2];
    const float* flow = (const float*)d_in[3];
    const float* w1 = (const float*)d_in[4];  const float* b1 = (const float*)d_in[5];
    const float* w2 = (const float*)d_in[6];  const float* b2 = (const float*)d_in[7];
    const float* w3 = (const float*)d_in[8];  const float* b3 = (const float*)d_in[9];
    const float* w4 = (const float*)d_in[10]; const float* b4 = (const float*)d_in[11];
    const float* dw = (const float*)d_in[12]; const float* db = (const float*)d_in[13];

    float* ws = (float*)d_ws;
    const size_t FEAT = (size_t)BB * 64 * HWSZ;       // 4,194,304 floats
    float* h1   = ws;                                 // conv1 out / conv3 out (reused)
    float* h2   = ws + FEAT;                          // conv2 out
    float* off4 = ws + 2 * FEAT;                      // 4*432*128*128 floats

    dim3 blk(256);

    // conv1: 130 -> 64, lrelu
    conv1_k<10, 16><<<dim3(8, 8, BB * 4), blk, 0, stream>>>(xfw, xc, flow, w1, b1, h1);
    // conv2: 64 -> 64, lrelu
    conv64_k<8, 16, 0><<<dim3(8, 8, BB * 4), blk, 0, stream>>>(h1, w2, b2, h2, 4, 64, nullptr);
    // conv3: 64 -> 64, lrelu   (h3 reuses h1)
    conv64_k<8, 16, 0><<<dim3(8, 8, BB * 4), blk, 0, stream>>>(h2, w3, b3, h1, 4, 64, nullptr);
    // conv4: 64 -> 432, fused offset/mask transform
    conv64_k<8, 16, 1><<<dim3(8, 8, BB * 27), blk, 0, stream>>>(h1, w4, b4, off4, 27, 432, flow);
    // deformable conv -> d_out
    dcn_k<<<dim3(8, 8, BB * 2), blk, 0, stream>>>(x, off4, dw, db, (float*)d_out);
}

// Round 2
// 1810.366 us; speedup vs baseline: 2.8840x; 2.8840x over previous
//
#include <hip/hip_runtime.h>
#include <math.h>

#define HH 128
#define WW 128
#define BB 4
#define HWSZ (HH*WW)

__device__ __forceinline__ float lrelu_f(float v) { return v >= 0.0f ? v : 0.1f * v; }

// ---------------------------------------------------------------------------
// Register-tiled 3x3 SAME conv, CIN=64 (conv2/3/4).
// Block: 256 threads = 16x16; each thread computes 2x2 pixels x 8 out chans.
// Tile: 32x32 pixels. EPI 0 = lrelu, EPI 1 = conv4 offset/mask transform.
// ---------------------------------------------------------------------------
template<int EPI>
__global__ __launch_bounds__(256, 2)
void conv_tile_k(const float* __restrict__ in, const float* __restrict__ wgt,
                 const float* __restrict__ bias, float* __restrict__ out,
                 int ocgCount, int OC, const float* __restrict__ flow)
{
    constexpr int CIN = 64;
    constexpr int CH = 4;
    const int tid = threadIdx.x;
    const int tx = tid & 15, ty = tid >> 4;
    const int b   = blockIdx.z / ocgCount;
    const int ocg = blockIdx.z - b * ocgCount;
    const int ocBase = ocg * 8;
    const int x0 = blockIdx.x * 32, y0 = blockIdx.y * 32;
    const int px = x0 + tx * 2, py = y0 + ty * 2;

    __shared__ float s_in[CH][34][34];
    __shared__ __align__(16) float s_w[CH][8][12];

    float acc[8][4];
#pragma unroll
    for (int o = 0; o < 8; ++o)
#pragma unroll
        for (int p = 0; p < 4; ++p) acc[o][p] = 0.0f;

    for (int cc = 0; cc < CIN; cc += CH) {
        __syncthreads();
        for (int idx = tid; idx < CH * 34 * 34; idx += 256) {
            int c = idx / 1156; int r = idx - c * 1156;
            int iy = r / 34;    int ix = r - iy * 34;
            int gy = y0 + iy - 1, gx = x0 + ix - 1;
            float v = 0.0f;
            if (gy >= 0 && gy < HH && gx >= 0 && gx < WW)
                v = in[((size_t)(b * CIN + cc + c) * HH + gy) * WW + gx];
            s_in[c][iy][ix] = v;
        }
        for (int idx = tid; idx < CH * 8 * 9; idx += 256) {
            int c = idx / 72; int r = idx - c * 72;
            int o = r / 9;    int k = r - o * 9;
            s_w[c][o][k] = wgt[((size_t)(ocBase + o) * CIN + cc + c) * 9 + k];
        }
        __syncthreads();
#pragma unroll
        for (int c = 0; c < CH; ++c) {
            float t[4][4];
#pragma unroll
            for (int r = 0; r < 4; ++r) {
                float2 a0 = *(const float2*)&s_in[c][ty*2 + r][tx*2];
                float2 a1 = *(const float2*)&s_in[c][ty*2 + r][tx*2 + 2];
                t[r][0] = a0.x; t[r][1] = a0.y; t[r][2] = a1.x; t[r][3] = a1.y;
            }
#pragma unroll
            for (int o = 0; o < 8; ++o) {
                const float4 w0 = *(const float4*)&s_w[c][o][0];
                const float4 w1 = *(const float4*)&s_w[c][o][4];
                const float  w8 = s_w[c][o][8];
                const float w9[9] = {w0.x, w0.y, w0.z, w0.w, w1.x, w1.y, w1.z, w1.w, w8};
#pragma unroll
                for (int pr = 0; pr < 2; ++pr)
#pragma unroll
                    for (int pc = 0; pc < 2; ++pc) {
                        float s = acc[o][pr*2 + pc];
#pragma unroll
                        for (int dy = 0; dy < 3; ++dy)
#pragma unroll
                            for (int dx = 0; dx < 3; ++dx)
                                s = fmaf(t[pr+dy][pc+dx], w9[dy*3+dx], s);
                        acc[o][pr*2 + pc] = s;
                    }
            }
        }
    }

#pragma unroll
    for (int o = 0; o < 8; ++o) {
        const int oc = ocBase + o;
        const float bv = bias[oc];
#pragma unroll
        for (int pr = 0; pr < 2; ++pr) {
            float v0 = acc[o][pr*2 + 0] + bv;
            float v1 = acc[o][pr*2 + 1] + bv;
            if (EPI == 0) {
                v0 = lrelu_f(v0); v1 = lrelu_f(v1);
            } else {
                if (oc < 288) {
                    const int fch = (oc & 1) ^ 1;   // flow_yx: even oc -> flow ch1
                    const float* fp = &flow[((size_t)(b*2 + fch) * HH + (py+pr)) * WW + px];
                    v0 = 10.0f * tanhf(v0) + fp[0];
                    v1 = 10.0f * tanhf(v1) + fp[1];
                } else {
                    v0 = 1.0f / (1.0f + expf(-v0));
                    v1 = 1.0f / (1.0f + expf(-v1));
                }
            }
            *(float2*)&out[((size_t)(b*OC + oc) * HH + (py+pr)) * WW + px] = make_float2(v0, v1);
        }
    }
}

// ---------------------------------------------------------------------------
// conv1: 130 inputs gathered from [x_flow_warped(64) | x_current(64) | flow(2)]
// Same register-tile structure.
// ---------------------------------------------------------------------------
__global__ __launch_bounds__(256, 2)
void conv1_tile_k(const float* __restrict__ xfw, const float* __restrict__ xc,
                  const float* __restrict__ flow, const float* __restrict__ wgt,
                  const float* __restrict__ bias, float* __restrict__ out)
{
    constexpr int CIN = 130;
    constexpr int CH = 4;
    const int tid = threadIdx.x;
    const int tx = tid & 15, ty = tid >> 4;
    const int b   = blockIdx.z >> 3;          // 64/8 = 8 oc groups
    const int ocBase = (blockIdx.z & 7) * 8;
    const int x0 = blockIdx.x * 32, y0 = blockIdx.y * 32;
    const int px = x0 + tx * 2, py = y0 + ty * 2;

    __shared__ float s_in[CH][34][34];
    __shared__ __align__(16) float s_w[CH][8][12];

    float acc[8][4];
#pragma unroll
    for (int o = 0; o < 8; ++o)
#pragma unroll
        for (int p = 0; p < 4; ++p) acc[o][p] = 0.0f;

    for (int cc = 0; cc < CIN; cc += CH) {    // 33 chunks, last partial
        __syncthreads();
        for (int idx = tid; idx < CH * 34 * 34; idx += 256) {
            int c = idx / 1156; int r = idx - c * 1156;
            int iy = r / 34;    int ix = r - iy * 34;
            int gy = y0 + iy - 1, gx = x0 + ix - 1;
            int ci = cc + c;
            float v = 0.0f;
            if (ci < CIN && gy >= 0 && gy < HH && gx >= 0 && gx < WW) {
                if (ci < 64)       v = xfw[((size_t)(b*64 + ci)       * HH + gy) * WW + gx];
                else if (ci < 128) v = xc [((size_t)(b*64 + ci - 64)  * HH + gy) * WW + gx];
                else               v = flow[((size_t)(b*2 + ci - 128) * HH + gy) * WW + gx];
            }
            s_in[c][iy][ix] = v;
        }
        for (int idx = tid; idx < CH * 8 * 9; idx += 256) {
            int c = idx / 72; int r = idx - c * 72;
            int o = r / 9;    int k = r - o * 9;
            int ci = cc + c;
            s_w[c][o][k] = (ci < CIN) ? wgt[((size_t)(ocBase + o) * CIN + ci) * 9 + k] : 0.0f;
        }
        __syncthreads();
#pragma unroll
        for (int c = 0; c < CH; ++c) {
            float t[4][4];
#pragma unroll
            for (int r = 0; r < 4; ++r) {
                float2 a0 = *(const float2*)&s_in[c][ty*2 + r][tx*2];
                float2 a1 = *(const float2*)&s_in[c][ty*2 + r][tx*2 + 2];
                t[r][0] = a0.x; t[r][1] = a0.y; t[r][2] = a1.x; t[r][3] = a1.y;
            }
#pragma unroll
            for (int o = 0; o < 8; ++o) {
                const float4 w0 = *(const float4*)&s_w[c][o][0];
                const float4 w1 = *(const float4*)&s_w[c][o][4];
                const float  w8 = s_w[c][o][8];
                const float w9[9] = {w0.x, w0.y, w0.z, w0.w, w1.x, w1.y, w1.z, w1.w, w8};
#pragma unroll
                for (int pr = 0; pr < 2; ++pr)
#pragma unroll
                    for (int pc = 0; pc < 2; ++pc) {
                        float s = acc[o][pr*2 + pc];
#pragma unroll
                        for (int dy = 0; dy < 3; ++dy)
#pragma unroll
                            for (int dx = 0; dx < 3; ++dx)
                                s = fmaf(t[pr+dy][pc+dx], w9[dy*3+dx], s);
                        acc[o][pr*2 + pc] = s;
                    }
            }
        }
    }

#pragma unroll
    for (int o = 0; o < 8; ++o) {
        const int oc = ocBase + o;
        const float bv = bias[oc];
#pragma unroll
        for (int pr = 0; pr < 2; ++pr) {
            float v0 = lrelu_f(acc[o][pr*2 + 0] + bv);
            float v1 = lrelu_f(acc[o][pr*2 + 1] + bv);
            *(float2*)&out[((size_t)(b*64 + oc) * HH + (py+pr)) * WW + px] = make_float2(v0, v1);
        }
    }
}

// ---------------------------------------------------------------------------
// deformable conv (unchanged from R1)
// ---------------------------------------------------------------------------
__global__ __launch_bounds__(256)
void dcn_k(const float* __restrict__ x, const float* __restrict__ o4,
           const float* __restrict__ wgt, const float* __restrict__ bias,
           float* __restrict__ out)
{
    const int tid = threadIdx.x;
    const int tx = tid & 15, ty = tid >> 4;
    const int bz = blockIdx.z;          // b*2 + ocg
    const int b = bz >> 1;
    const int ocBase = (bz & 1) * 32;
    const int px = blockIdx.x * 16 + tx, py = blockIdx.y * 16 + ty;
    const int pix = py * WW + px;

    __shared__ __align__(16) float s_w[32][9][4];   // [oc][k][cg]

    float acc[32];
#pragma unroll
    for (int o = 0; o < 32; ++o) acc[o] = 0.0f;

    const float* offp = o4 + (size_t)b * 432 * HWSZ;
    const float* xb   = x  + (size_t)b * 64  * HWSZ;

    for (int dg = 0; dg < 16; ++dg) {
        __syncthreads();
        for (int idx = tid; idx < 32 * 36; idx += 256) {
            int o = idx / 36; int r = idx - o * 36;
            int k = r >> 2; int cg = r & 3;
            s_w[o][k][cg] = wgt[((size_t)(ocBase + o) * 64 + dg*4 + cg) * 9 + k];
        }
        __syncthreads();
#pragma unroll
        for (int k = 0; k < 9; ++k) {
            int ch2 = (dg * 9 + k) * 2;
            float oy = offp[(size_t)ch2       * HWSZ + pix];
            float ox = offp[(size_t)(ch2 + 1) * HWSZ + pix];
            float m  = offp[(size_t)(288 + dg*9 + k) * HWSZ + pix];
            float ys = (float)py + (float)(k / 3 - 1) + oy;
            float xs = (float)px + (float)(k % 3 - 1) + ox;
            float y0f = floorf(ys), x0f = floorf(xs);
            float wy = ys - y0f,    wx = xs - x0f;
            int y0 = (int)y0f, x0i = (int)x0f;
            int y1 = y0 + 1,   x1  = x0i + 1;
            float fy0 = (y0 >= 0 && y0 < HH) ? 1.0f : 0.0f;
            float fy1 = (y1 >= 0 && y1 < HH) ? 1.0f : 0.0f;
            float fx0 = (x0i >= 0 && x0i < WW) ? 1.0f : 0.0f;
            float fx1 = (x1 >= 0 && x1 < WW) ? 1.0f : 0.0f;
            int yc0 = min(max(y0, 0), HH-1), yc1 = min(max(y1, 0), HH-1);
            int xc0 = min(max(x0i,0), WW-1), xc1 = min(max(x1, 0), WW-1);
            float f00 = fy0 * fx0, f01 = fy0 * fx1, f10 = fy1 * fx0, f11 = fy1 * fx1;
            float sv[4];
#pragma unroll
            for (int cg = 0; cg < 4; ++cg) {
                const float* xp = xb + (size_t)(dg*4 + cg) * HWSZ;
                float v00 = xp[yc0 * WW + xc0] * f00;
                float v01 = xp[yc0 * WW + xc1] * f01;
                float v10 = xp[yc1 * WW + xc0] * f10;
                float v11 = xp[yc1 * WW + xc1] * f11;
                float top = v00 * (1.0f - wx) + v01 * wx;
                float bot = v10 * (1.0f - wx) + v11 * wx;
                sv[cg] = (top * (1.0f - wy) + bot * wy) * m;
            }
#pragma unroll
            for (int o = 0; o < 32; ++o) {
                const float4 wv = *(const float4*)&s_w[o][k][0];
                acc[o] = fmaf(sv[0], wv.x,
                          fmaf(sv[1], wv.y,
                           fmaf(sv[2], wv.z,
                            fmaf(sv[3], wv.w, acc[o]))));
            }
        }
    }

#pragma unroll
    for (int o = 0; o < 32; ++o) {
        int oc = ocBase + o;
        out[(size_t)(b*64 + oc) * HWSZ + pix] = acc[o] + bias[oc];
    }
}

// ---------------------------------------------------------------------------
extern "C" void kernel_launch(void* const* d_in, const int* in_sizes, int n_in,
                              void* d_out, int out_size, void* d_ws, size_t ws_size,
                              hipStream_t stream)
{
    const float* x    = (const float*)d_in[0];
    const float* xfw  = (const float*)d_in[1];
    const float* xc   = (const float*)d_in[2];
    const float* flow = (const float*)d_in[3];
    const float* w1 = (const float*)d_in[4];  const float* b1 = (const float*)d_in[5];
    const float* w2 = (const float*)d_in[6];  const float* b2 = (const float*)d_in[7];
    const float* w3 = (const float*)d_in[8];  const float* b3 = (const float*)d_in[9];
    const float* w4 = (const float*)d_in[10]; const float* b4 = (const float*)d_in[11];
    const float* dw = (const float*)d_in[12]; const float* db = (const float*)d_in[13];

    float* ws = (float*)d_ws;
    const size_t FEAT = (size_t)BB * 64 * HWSZ;
    float* h1   = ws;
    float* h2   = ws + FEAT;
    float* off4 = ws + 2 * FEAT;

    dim3 blk(256);

    // conv1: 130 -> 64, lrelu
    conv1_tile_k<<<dim3(4, 4, BB * 8), blk, 0, stream>>>(xfw, xc, flow, w1, b1, h1);
    // conv2: 64 -> 64, lrelu
    conv_tile_k<0><<<dim3(4, 4, BB * 8), blk, 0, stream>>>(h1, w2, b2, h2, 8, 64, nullptr);
    // conv3: 64 -> 64, lrelu   (reuses h1)
    conv_tile_k<0><<<dim3(4, 4, BB * 8), blk, 0, stream>>>(h2, w3, b3, h1, 8, 64, nullptr);
    // conv4: 64 -> 432, fused offset/mask transform
    conv_tile_k<1><<<dim3(4, 4, BB * 54), blk, 0, stream>>>(h1, w4, b4, off4, 54, 432, flow);
    // deformable conv -> d_out
    dcn_k<<<dim3(8, 8, BB * 2), blk, 0, stream>>>(x, off4, dw, db, (float*)d_out);
}

// Round 3
// 956.322 us; speedup vs baseline: 5.4596x; 1.8931x over previous
//
#include <hip/hip_runtime.h>
#include <math.h>

#define HH 128
#define WW 128
#define BB 4
#define HWSZ (HH*WW)

typedef __bf16 bf16_t;
typedef bf16_t bf16x8 __attribute__((ext_vector_type(8)));
typedef float  f32x16 __attribute__((ext_vector_type(16)));

__device__ __forceinline__ void split_bf16(float v, bf16_t& h, bf16_t& l) {
    h = (bf16_t)v;
    l = (bf16_t)(v - (float)h);
}
__device__ __forceinline__ float lrelu_f(float v) { return v >= 0.0f ? v : 0.1f * v; }

// ---------------------------------------------------------------------------
// pack A0: [xfw(64) | xc(64) | flow(2) | zeros(30)] -> NHWC bf16 hi/lo, CINP=160
// layout: a0[pix][plane(2)][160]
// ---------------------------------------------------------------------------
__global__ __launch_bounds__(256)
void pack_a0_k(const float* __restrict__ xfw, const float* __restrict__ xc,
               const float* __restrict__ flow, bf16_t* __restrict__ a0)
{
    int idx = blockIdx.x * 256 + threadIdx.x;           // BB*HWSZ*160 total
    if (idx >= BB * HWSZ * 160) return;
    int c = idx % 160; int pix = idx / 160;
    int b = pix >> 14; int p = pix & 16383;
    float v = 0.0f;
    if (c < 64)       v = xfw[(size_t)(b*64 + c) * HWSZ + p];
    else if (c < 128) v = xc [(size_t)(b*64 + c - 64) * HWSZ + p];
    else if (c < 130) v = flow[(size_t)(b*2 + c - 128) * HWSZ + p];
    bf16_t h, l; split_bf16(v, h, l);
    size_t base = (size_t)pix * 320 + c;
    a0[base]       = h;
    a0[base + 160] = l;
}

// ---------------------------------------------------------------------------
// pack weights: W[oc][cin][3][3] fp32 -> Wp[tap(9)][ocP][plane(2)][cinP] bf16
// zero-padded for oc>=OC or cin>=CIN.
// ---------------------------------------------------------------------------
__global__ __launch_bounds__(256)
void pack_w_k(const float* __restrict__ w, bf16_t* __restrict__ wp,
              int OC, int CIN, int OCP, int CINP)
{
    int idx = blockIdx.x * 256 + threadIdx.x;           // 9*OCP*CINP total
    if (idx >= 9 * OCP * CINP) return;
    int c = idx % CINP; int r = idx / CINP;
    int oc = r % OCP;   int tap = r / OCP;
    float v = (oc < OC && c < CIN) ? w[((size_t)oc * CIN + c) * 9 + tap] : 0.0f;
    bf16_t h, l; split_bf16(v, h, l);
    size_t base = (((size_t)tap * OCP + oc) * 2) * CINP + c;
    wp[base]        = h;
    wp[base + CINP] = l;
}

// ---------------------------------------------------------------------------
// MFMA implicit-GEMM 3x3 SAME conv.
// A: NHWC packed bf16 hi/lo [pix][2][CINP]; Wp: [tap][OCP][2][CINP].
// Block: 256 thr = 4 waves; patch 16x16 px; wave w owns patch rows [4w,4w+4).
// Wave tile: M=64 px (2 mtiles of 32) x N=64 oc (2 ntiles of 32) -> 64 acc.
// Split-fp32: acc += Ahi*Bhi + Alo*Bhi + Ahi*Blo (3 MFMAs / k-step / tile).
// EPI 0: lrelu -> packed NHWC bf16 hi/lo out (CINP_out=64).
// EPI 1: conv4 transform -> fp32 NCHW (10*tanh+flow_yx for oc<288, sigmoid).
// ---------------------------------------------------------------------------
template<int CINP, int EPI>
__global__ __launch_bounds__(256, 2)
void conv_mfma_k(const bf16_t* __restrict__ A, const bf16_t* __restrict__ Wp,
                 const float* __restrict__ bias, void* __restrict__ outv,
                 int OCP, int OC, const float* __restrict__ flow)
{
    constexpr int NKC = CINP / 32;          // k-chunks of 32 channels
    constexpr int PSTR = 72;                // 2*32 + 8 pad (bf16 units) per halo pixel
    const int tid  = threadIdx.x;
    const int lane = tid & 63;
    const int wv   = tid >> 6;
    const int b     = blockIdx.y;
    const int patch = blockIdx.x;                       // 8x8 patches of 16x16
    const int y0 = (patch >> 3) * 16, x0 = (patch & 7) * 16;
    const int ocBase = blockIdx.z * 64;

    __shared__ __align__(16) bf16_t s_a[324 * PSTR];    // 18x18 halo x 32ch x 2pl

    f32x16 acc[2][2];
#pragma unroll
    for (int mt = 0; mt < 2; ++mt)
#pragma unroll
        for (int nt = 0; nt < 2; ++nt)
#pragma unroll
            for (int r = 0; r < 16; ++r) acc[mt][nt][r] = 0.0f;

    // A-fragment lane mapping: m = lane&31 -> (row m>>4, col m&15); k = (lane>>5)*8+j
    const int m     = lane & 31;
    const int klane = lane >> 5;
    const int pyy0  = wv * 4 + (m >> 4);
    const int pxx   = m & 15;
    const int abase0 = ((pyy0    ) * 18 + pxx) * PSTR + klane * 8;   // mtile 0
    const int abase1 = ((pyy0 + 2) * 18 + pxx) * PSTR + klane * 8;   // mtile 1

    // B-fragment lane mapping: n = lane&31, k = (lane>>5)*8+j
    const bf16_t* blane = Wp + ((size_t)(ocBase + m) * 2) * CINP + klane * 8;

    for (int kc = 0; kc < NKC; ++kc) {
        __syncthreads();
        // stage A k-chunk: 324 halo px x 2 planes x 32 ch (vec8 units = 2592)
        for (int i = tid; i < 324 * 8; i += 256) {
            int pix = i >> 3; int sub = i & 7;          // pl = sub>>2, c8 = sub&3
            int hy = pix / 18, hx = pix - hy * 18;
            int gy = y0 + hy - 1, gx = x0 + hx - 1;
            bf16x8 v = {(bf16_t)0.f,(bf16_t)0.f,(bf16_t)0.f,(bf16_t)0.f,
                        (bf16_t)0.f,(bf16_t)0.f,(bf16_t)0.f,(bf16_t)0.f};
            if (gy >= 0 && gy < HH && gx >= 0 && gx < WW) {
                size_t ga = ((size_t)(b * HWSZ + gy * WW + gx) * 2 + (sub >> 2)) * CINP
                            + kc * 32 + (sub & 3) * 8;
                v = *(const bf16x8*)(A + ga);
            }
            *(bf16x8*)(s_a + pix * PSTR + (sub >> 2) * 32 + (sub & 3) * 8) = v;
        }
        __syncthreads();

#pragma unroll
        for (int tap = 0; tap < 9; ++tap) {
            const int dy = tap / 3, dx = tap % 3;
            const int aoff = (dy * 18 + dx) * PSTR;
            const bf16_t* bpt = blane + (size_t)tap * OCP * 2 * CINP + kc * 32;
#pragma unroll
            for (int ks = 0; ks < 2; ++ks) {
                bf16x8 bfr[2][2];
#pragma unroll
                for (int nt = 0; nt < 2; ++nt)
#pragma unroll
                    for (int pl = 0; pl < 2; ++pl)
                        bfr[nt][pl] = *(const bf16x8*)(bpt + (size_t)nt * 64 * CINP
                                                       + pl * CINP + ks * 16);
                bf16x8 afr[2][2];
#pragma unroll
                for (int pl = 0; pl < 2; ++pl) {
                    afr[0][pl] = *(const bf16x8*)(s_a + abase0 + aoff + pl * 32 + ks * 16);
                    afr[1][pl] = *(const bf16x8*)(s_a + abase1 + aoff + pl * 32 + ks * 16);
                }
#pragma unroll
                for (int mt = 0; mt < 2; ++mt)
#pragma unroll
                    for (int nt = 0; nt < 2; ++nt) {
                        acc[mt][nt] = __builtin_amdgcn_mfma_f32_32x32x16_bf16(
                            afr[mt][0], bfr[nt][0], acc[mt][nt], 0, 0, 0);
                        acc[mt][nt] = __builtin_amdgcn_mfma_f32_32x32x16_bf16(
                            afr[mt][1], bfr[nt][0], acc[mt][nt], 0, 0, 0);
                        acc[mt][nt] = __builtin_amdgcn_mfma_f32_32x32x16_bf16(
                            afr[mt][0], bfr[nt][1], acc[mt][nt], 0, 0, 0);
                    }
            }
        }
    }

    // epilogue — C layout: col = lane&31 (oc), row = (r&3)+8*(r>>2)+4*(lane>>5)
    const int n_l = lane & 31;
#pragma unroll
    for (int nt = 0; nt < 2; ++nt) {
        const int oc = ocBase + nt * 32 + n_l;
        if (EPI == 1 && oc >= OC) continue;
        const float bv = bias[oc];
#pragma unroll
        for (int mt = 0; mt < 2; ++mt) {
#pragma unroll
            for (int r = 0; r < 16; ++r) {
                const int row = (r & 3) + 8 * (r >> 2) + 4 * klane;   // 0..31
                const int pyy = wv * 4 + mt * 2 + (row >> 4);
                const int gy = y0 + pyy, gx = x0 + (row & 15);
                const size_t pixg = (size_t)b * HWSZ + gy * WW + gx;
                float v = acc[mt][nt][r] + bv;
                if (EPI == 0) {
                    v = lrelu_f(v);
                    bf16_t h, l; split_bf16(v, h, l);
                    bf16_t* o = (bf16_t*)outv;
                    size_t base = pixg * 128 + oc;      // [pix][pl][64]
                    o[base]      = h;
                    o[base + 64] = l;
                } else {
                    float* o = (float*)outv;
                    if (oc < 288) {
                        const int fch = (oc & 1) ^ 1;   // flow_yx
                        float fl = flow[(size_t)(b*2 + fch) * HWSZ + gy * WW + gx];
                        v = 10.0f * tanhf(v) + fl;
                    } else {
                        v = 1.0f / (1.0f + expf(-v));
                    }
                    o[(size_t)(b * 432 + oc) * HWSZ + gy * WW + gx] = v;
                }
            }
        }
    }
}

// ---------------------------------------------------------------------------
// deformable conv (unchanged from R2)
// ---------------------------------------------------------------------------
__global__ __launch_bounds__(256)
void dcn_k(const float* __restrict__ x, const float* __restrict__ o4,
           const float* __restrict__ wgt, const float* __restrict__ bias,
           float* __restrict__ out)
{
    const int tid = threadIdx.x;
    const int tx = tid & 15, ty = tid >> 4;
    const int bz = blockIdx.z;          // b*2 + ocg
    const int b = bz >> 1;
    const int ocBase = (bz & 1) * 32;
    const int px = blockIdx.x * 16 + tx, py = blockIdx.y * 16 + ty;
    const int pix = py * WW + px;

    __shared__ __align__(16) float s_w[32][9][4];   // [oc][k][cg]

    float acc[32];
#pragma unroll
    for (int o = 0; o < 32; ++o) acc[o] = 0.0f;

    const float* offp = o4 + (size_t)b * 432 * HWSZ;
    const float* xb   = x  + (size_t)b * 64  * HWSZ;

    for (int dg = 0; dg < 16; ++dg) {
        __syncthreads();
        for (int idx = tid; idx < 32 * 36; idx += 256) {
            int o = idx / 36; int r = idx - o * 36;
            int k = r >> 2; int cg = r & 3;
            s_w[o][k][cg] = wgt[((size_t)(ocBase + o) * 64 + dg*4 + cg) * 9 + k];
        }
        __syncthreads();
#pragma unroll
        for (int k = 0; k < 9; ++k) {
            int ch2 = (dg * 9 + k) * 2;
            float oy = offp[(size_t)ch2       * HWSZ + pix];
            float ox = offp[(size_t)(ch2 + 1) * HWSZ + pix];
            float mk = offp[(size_t)(288 + dg*9 + k) * HWSZ + pix];
            float ys = (float)py + (float)(k / 3 - 1) + oy;
            float xs = (float)px + (float)(k % 3 - 1) + ox;
            float y0f = floorf(ys), x0f = floorf(xs);
            float wy = ys - y0f,    wx = xs - x0f;
            int y0 = (int)y0f, x0i = (int)x0f;
            int y1 = y0 + 1,   x1  = x0i + 1;
            float fy0 = (y0 >= 0 && y0 < HH) ? 1.0f : 0.0f;
            float fy1 = (y1 >= 0 && y1 < HH) ? 1.0f : 0.0f;
            float fx0 = (x0i >= 0 && x0i < WW) ? 1.0f : 0.0f;
            float fx1 = (x1 >= 0 && x1 < WW) ? 1.0f : 0.0f;
            int yc0 = min(max(y0, 0), HH-1), yc1 = min(max(y1, 0), HH-1);
            int xc0 = min(max(x0i,0), WW-1), xc1 = min(max(x1, 0), WW-1);
            float f00 = fy0 * fx0, f01 = fy0 * fx1, f10 = fy1 * fx0, f11 = fy1 * fx1;
            float sv[4];
#pragma unroll
            for (int cg = 0; cg < 4; ++cg) {
                const float* xp = xb + (size_t)(dg*4 + cg) * HWSZ;
                float v00 = xp[yc0 * WW + xc0] * f00;
                float v01 = xp[yc0 * WW + xc1] * f01;
                float v10 = xp[yc1 * WW + xc0] * f10;
                float v11 = xp[yc1 * WW + xc1] * f11;
                float top = v00 * (1.0f - wx) + v01 * wx;
                float bot = v10 * (1.0f - wx) + v11 * wx;
                sv[cg] = (top * (1.0f - wy) + bot * wy) * mk;
            }
#pragma unroll
            for (int o = 0; o < 32; ++o) {
                const float4 wv = *(const float4*)&s_w[o][k][0];
                acc[o] = fmaf(sv[0], wv.x,
                          fmaf(sv[1], wv.y,
                           fmaf(sv[2], wv.z,
                            fmaf(sv[3], wv.w, acc[o]))));
            }
        }
    }

#pragma unroll
    for (int o = 0; o < 32; ++o) {
        int oc = ocBase + o;
        out[(size_t)(b*64 + oc) * HWSZ + pix] = acc[o] + bias[oc];
    }
}

// ---------------------------------------------------------------------------
extern "C" void kernel_launch(void* const* d_in, const int* in_sizes, int n_in,
                              void* d_out, int out_size, void* d_ws, size_t ws_size,
                              hipStream_t stream)
{
    const float* x    = (const float*)d_in[0];
    const float* xfw  = (const float*)d_in[1];
    const float* xc   = (const float*)d_in[2];
    const float* flow = (const float*)d_in[3];
    const float* w1 = (const float*)d_in[4];  const float* b1 = (const float*)d_in[5];
    const float* w2 = (const float*)d_in[6];  const float* b2 = (const float*)d_in[7];
    const float* w3 = (const float*)d_in[8];  const float* b3 = (const float*)d_in[9];
    const float* w4 = (const float*)d_in[10]; const float* b4 = (const float*)d_in[11];
    const float* dw = (const float*)d_in[12]; const float* db = (const float*)d_in[13];

    // workspace layout (bytes). A0 (41.9 MB) aliases the off4 region (113.2 MB):
    // A0 is dead after conv1; conv4 writes off4 afterwards. Total ~148.5 MB.
    char* wsb = (char*)d_ws;
    const size_t off4_bytes = (size_t)BB * 432 * HWSZ * 4;
    bf16_t* A0   = (bf16_t*)wsb;
    float*  off4 = (float*)wsb;
    char* p = wsb + off4_bytes;
    bf16_t* h1p = (bf16_t*)p;  p += (size_t)BB * HWSZ * 2 * 64 * 2;
    bf16_t* h2p = (bf16_t*)p;  p += (size_t)BB * HWSZ * 2 * 64 * 2;
    bf16_t* wp1 = (bf16_t*)p;  p += (size_t)9 * 64  * 2 * 160 * 2;
    bf16_t* wp2 = (bf16_t*)p;  p += (size_t)9 * 64  * 2 * 64  * 2;
    bf16_t* wp3 = (bf16_t*)p;  p += (size_t)9 * 64  * 2 * 64  * 2;
    bf16_t* wp4 = (bf16_t*)p;  p += (size_t)9 * 448 * 2 * 64  * 2;

    // pack weights + input
    pack_w_k<<<(9*64*160  + 255)/256, 256, 0, stream>>>(w1, wp1, 64, 130, 64, 160);
    pack_w_k<<<(9*64*64   + 255)/256, 256, 0, stream>>>(w2, wp2, 64, 64, 64, 64);
    pack_w_k<<<(9*64*64   + 255)/256, 256, 0, stream>>>(w3, wp3, 64, 64, 64, 64);
    pack_w_k<<<(9*448*64  + 255)/256, 256, 0, stream>>>(w4, wp4, 432, 64, 448, 64);
    pack_a0_k<<<(BB*HWSZ*160 + 255)/256, 256, 0, stream>>>(xfw, xc, flow, A0);

    // conv chain (MFMA)
    conv_mfma_k<160,0><<<dim3(64, BB, 1), 256, 0, stream>>>(A0,  wp1, b1, h1p, 64,  64,  nullptr);
    conv_mfma_k<64, 0><<<dim3(64, BB, 1), 256, 0, stream>>>(h1p, wp2, b2, h2p, 64,  64,  nullptr);
    conv_mfma_k<64, 0><<<dim3(64, BB, 1), 256, 0, stream>>>(h2p, wp3, b3, h1p, 64,  64,  nullptr);
    conv_mfma_k<64, 1><<<dim3(64, BB, 7), 256, 0, stream>>>(h1p, wp4, b4, off4, 448, 432, flow);

    // deformable conv -> d_out
    dcn_k<<<dim3(8, 8, BB * 2), 256, 0, stream>>>(x, off4, dw, db, (float*)d_out);
}

// Round 4
// 648.965 us; speedup vs baseline: 8.0454x; 1.4736x over previous
//
#include <hip/hip_runtime.h>
#include <math.h>

#define HH 128
#define WW 128
#define BB 4
#define HWSZ (HH*WW)

typedef __bf16 bf16_t;
typedef bf16_t bf16x8 __attribute__((ext_vector_type(8)));
typedef float  f32x16 __attribute__((ext_vector_type(16)));

__device__ __forceinline__ void split_bf16(float v, bf16_t& h, bf16_t& l) {
    h = (bf16_t)v;
    l = (bf16_t)(v - (float)h);
}
__device__ __forceinline__ float lrelu_f(float v) { return v >= 0.0f ? v : 0.1f * v; }

// ---------------------------------------------------------------------------
// pack A0: [xfw(64) | xc(64) | flow(2) | zeros(30)] -> NHWC bf16 hi/lo, CINP=160
// ---------------------------------------------------------------------------
__global__ __launch_bounds__(256)
void pack_a0_k(const float* __restrict__ xfw, const float* __restrict__ xc,
               const float* __restrict__ flow, bf16_t* __restrict__ a0)
{
    int idx = blockIdx.x * 256 + threadIdx.x;
    if (idx >= BB * HWSZ * 160) return;
    int c = idx % 160; int pix = idx / 160;
    int b = pix >> 14; int p = pix & 16383;
    float v = 0.0f;
    if (c < 64)       v = xfw[(size_t)(b*64 + c) * HWSZ + p];
    else if (c < 128) v = xc [(size_t)(b*64 + c - 64) * HWSZ + p];
    else if (c < 130) v = flow[(size_t)(b*2 + c - 128) * HWSZ + p];
    bf16_t h, l; split_bf16(v, h, l);
    size_t base = (size_t)pix * 320 + c;
    a0[base]       = h;
    a0[base + 160] = l;
}

// ---------------------------------------------------------------------------
// pack conv weights: W[oc][cin][3][3] fp32 -> Wp[tap][ocP][pl][cinP] bf16
// ---------------------------------------------------------------------------
__global__ __launch_bounds__(256)
void pack_w_k(const float* __restrict__ w, bf16_t* __restrict__ wp,
              int OC, int CIN, int OCP, int CINP)
{
    int idx = blockIdx.x * 256 + threadIdx.x;
    if (idx >= 9 * OCP * CINP) return;
    int c = idx % CINP; int r = idx / CINP;
    int oc = r % OCP;   int tap = r / OCP;
    float v = (oc < OC && c < CIN) ? w[((size_t)oc * CIN + c) * 9 + tap] : 0.0f;
    bf16_t h, l; split_bf16(v, h, l);
    size_t base = (((size_t)tap * OCP + oc) * 2) * CINP + c;
    wp[base]        = h;
    wp[base + CINP] = l;
}

// ---------------------------------------------------------------------------
// pack dcn weights: dw[oc64][cin64][3][3] -> Bp[dg16][ks3][oc64][pl2][16] bf16
// K-index within dg: kk = tap*4+cg (tap 0..11, taps>=9 zero), ks = kk>>4.
// ---------------------------------------------------------------------------
__global__ __launch_bounds__(256)
void pack_dw_k(const float* __restrict__ dw, bf16_t* __restrict__ Bp)
{
    int idx = blockIdx.x * 256 + threadIdx.x;
    if (idx >= 16 * 48 * 64) return;
    int oc = idx & 63; int rest = idx >> 6;
    int kk = rest % 48; int dg = rest / 48;
    int tap = kk >> 2, cg = kk & 3;
    int ks = kk >> 4,  kj = kk & 15;
    float v = (tap < 9) ? dw[((size_t)oc * 64 + dg*4 + cg) * 9 + tap] : 0.0f;
    bf16_t h, l; split_bf16(v, h, l);
    size_t base = (((size_t)(dg*3 + ks) * 64 + oc) * 2) * 16 + kj;
    Bp[base]      = h;
    Bp[base + 16] = l;
}

// ---------------------------------------------------------------------------
// transpose x NCHW fp32 -> xT NHWC fp32 [b][pix][64]
// ---------------------------------------------------------------------------
__global__ __launch_bounds__(256)
void pack_xt_k(const float* __restrict__ x, float* __restrict__ xT)
{
    __shared__ float s[64][65];
    const int tid = threadIdx.x;
    const int p0 = blockIdx.x * 64;          // 1024 blocks x 64 pixels
    const int b = p0 >> 14, pp = p0 & 16383;
    for (int i = tid; i < 4096; i += 256) {
        int c = i >> 6, p = i & 63;
        s[p][c] = x[((size_t)(b*64 + c) << 14) + pp + p];
    }
    __syncthreads();
    for (int i = tid; i < 4096; i += 256) {
        int p = i >> 6, c = i & 63;
        xT[((size_t)(b << 14) + pp + p) * 64 + c] = s[p][c];
    }
}

// ---------------------------------------------------------------------------
// MFMA implicit-GEMM 3x3 SAME conv (unchanged from R3).
// ---------------------------------------------------------------------------
template<int CINP, int EPI>
__global__ __launch_bounds__(256, 2)
void conv_mfma_k(const bf16_t* __restrict__ A, const bf16_t* __restrict__ Wp,
                 const float* __restrict__ bias, void* __restrict__ outv,
                 int OCP, int OC, const float* __restrict__ flow)
{
    constexpr int NKC = CINP / 32;
    constexpr int PSTR = 72;
    const int tid  = threadIdx.x;
    const int lane = tid & 63;
    const int wv   = tid >> 6;
    const int b     = blockIdx.y;
    const int patch = blockIdx.x;
    const int y0 = (patch >> 3) * 16, x0 = (patch & 7) * 16;
    const int ocBase = blockIdx.z * 64;

    __shared__ __align__(16) bf16_t s_a[324 * PSTR];

    f32x16 acc[2][2];
#pragma unroll
    for (int mt = 0; mt < 2; ++mt)
#pragma unroll
        for (int nt = 0; nt < 2; ++nt)
#pragma unroll
            for (int r = 0; r < 16; ++r) acc[mt][nt][r] = 0.0f;

    const int m     = lane & 31;
    const int klane = lane >> 5;
    const int pyy0  = wv * 4 + (m >> 4);
    const int pxx   = m & 15;
    const int abase0 = ((pyy0    ) * 18 + pxx) * PSTR + klane * 8;
    const int abase1 = ((pyy0 + 2) * 18 + pxx) * PSTR + klane * 8;

    const bf16_t* blane = Wp + ((size_t)(ocBase + m) * 2) * CINP + klane * 8;

    for (int kc = 0; kc < NKC; ++kc) {
        __syncthreads();
        for (int i = tid; i < 324 * 8; i += 256) {
            int pix = i >> 3; int sub = i & 7;
            int hy = pix / 18, hx = pix - hy * 18;
            int gy = y0 + hy - 1, gx = x0 + hx - 1;
            bf16x8 v = {(bf16_t)0.f,(bf16_t)0.f,(bf16_t)0.f,(bf16_t)0.f,
                        (bf16_t)0.f,(bf16_t)0.f,(bf16_t)0.f,(bf16_t)0.f};
            if (gy >= 0 && gy < HH && gx >= 0 && gx < WW) {
                size_t ga = ((size_t)(b * HWSZ + gy * WW + gx) * 2 + (sub >> 2)) * CINP
                            + kc * 32 + (sub & 3) * 8;
                v = *(const bf16x8*)(A + ga);
            }
            *(bf16x8*)(s_a + pix * PSTR + (sub >> 2) * 32 + (sub & 3) * 8) = v;
        }
        __syncthreads();

#pragma unroll
        for (int tap = 0; tap < 9; ++tap) {
            const int dy = tap / 3, dx = tap % 3;
            const int aoff = (dy * 18 + dx) * PSTR;
            const bf16_t* bpt = blane + (size_t)tap * OCP * 2 * CINP + kc * 32;
#pragma unroll
            for (int ks = 0; ks < 2; ++ks) {
                bf16x8 bfr[2][2];
#pragma unroll
                for (int nt = 0; nt < 2; ++nt)
#pragma unroll
                    for (int pl = 0; pl < 2; ++pl)
                        bfr[nt][pl] = *(const bf16x8*)(bpt + (size_t)nt * 64 * CINP
                                                       + pl * CINP + ks * 16);
                bf16x8 afr[2][2];
#pragma unroll
                for (int pl = 0; pl < 2; ++pl) {
                    afr[0][pl] = *(const bf16x8*)(s_a + abase0 + aoff + pl * 32 + ks * 16);
                    afr[1][pl] = *(const bf16x8*)(s_a + abase1 + aoff + pl * 32 + ks * 16);
                }
#pragma unroll
                for (int mt = 0; mt < 2; ++mt)
#pragma unroll
                    for (int nt = 0; nt < 2; ++nt) {
                        acc[mt][nt] = __builtin_amdgcn_mfma_f32_32x32x16_bf16(
                            afr[mt][0], bfr[nt][0], acc[mt][nt], 0, 0, 0);
                        acc[mt][nt] = __builtin_amdgcn_mfma_f32_32x32x16_bf16(
                            afr[mt][1], bfr[nt][0], acc[mt][nt], 0, 0, 0);
                        acc[mt][nt] = __builtin_amdgcn_mfma_f32_32x32x16_bf16(
                            afr[mt][0], bfr[nt][1], acc[mt][nt], 0, 0, 0);
                    }
            }
        }
    }

    const int n_l = lane & 31;
#pragma unroll
    for (int nt = 0; nt < 2; ++nt) {
        const int oc = ocBase + nt * 32 + n_l;
        if (EPI == 1 && oc >= OC) continue;
        const float bv = bias[oc];
#pragma unroll
        for (int mt = 0; mt < 2; ++mt) {
#pragma unroll
            for (int r = 0; r < 16; ++r) {
                const int row = (r & 3) + 8 * (r >> 2) + 4 * klane;
                const int pyy = wv * 4 + mt * 2 + (row >> 4);
                const int gy = y0 + pyy, gx = x0 + (row & 15);
                const size_t pixg = (size_t)b * HWSZ + gy * WW + gx;
                float v = acc[mt][nt][r] + bv;
                if (EPI == 0) {
                    v = lrelu_f(v);
                    bf16_t h, l; split_bf16(v, h, l);
                    bf16_t* o = (bf16_t*)outv;
                    size_t base = pixg * 128 + oc;
                    o[base]      = h;
                    o[base + 64] = l;
                } else {
                    float* o = (float*)outv;
                    if (oc < 288) {
                        const int fch = (oc & 1) ^ 1;
                        float fl = flow[(size_t)(b*2 + fch) * HWSZ + gy * WW + gx];
                        v = 10.0f * tanhf(v) + fl;
                    } else {
                        v = 1.0f / (1.0f + expf(-v));
                    }
                    o[(size_t)(b * 432 + oc) * HWSZ + gy * WW + gx] = v;
                }
            }
        }
    }
}

// ---------------------------------------------------------------------------
// dcn as gather-into-MFMA-fragments.  Wave = 32 px (1 mtile) x 64 oc
// (2 ntiles); block = 4 waves = 16x8 pixel tile; grid 8x16x4 = 512 blocks.
// K per dg padded to 48 (12 taps x 4 cg; taps 9..11 zero): 3 k-steps of 16.
// Lane (m=lane&31, klane=lane>>5) gathers its own A-fragment: per k-step it
// owns taps {4ks+2klane, 4ks+2klane+1}; each tap = 4 corner dwordx4 loads
// from NHWC xT + bilinear combine + mask; split fp32 -> bf16 hi/lo frags.
// ---------------------------------------------------------------------------
__global__ __launch_bounds__(256, 2)
void dcn_mfma_k(const float* __restrict__ xT, const float* __restrict__ off4,
                const bf16_t* __restrict__ Bp, const float* __restrict__ bias,
                float* __restrict__ out)
{
    const int tid   = threadIdx.x;
    const int lane  = tid & 63;
    const int wv    = tid >> 6;
    const int klane = lane >> 5;
    const int m     = lane & 31;
    const int b     = blockIdx.z;
    const int tx0 = blockIdx.x * 16, ty0 = blockIdx.y * 8;
    const int py = ty0 + wv * 2 + (m >> 4);
    const int px = tx0 + (m & 15);
    const int pixoff = py * WW + px;

    const float* offb = off4 + (size_t)b * 432 * HWSZ;
    const float* xTb  = xT   + (size_t)b * HWSZ * 64;

    f32x16 acc[2];
#pragma unroll
    for (int nt = 0; nt < 2; ++nt)
#pragma unroll
        for (int r = 0; r < 16; ++r) acc[nt][r] = 0.0f;

    for (int dg = 0; dg < 16; ++dg) {
        bf16x8 Ah[3], Al[3];
#pragma unroll
        for (int ks = 0; ks < 3; ++ks) {
            float sv[8];
#pragma unroll
            for (int j = 0; j < 8; ++j) sv[j] = 0.0f;
#pragma unroll
            for (int tt = 0; tt < 2; ++tt) {
                const int tap = ks * 4 + klane * 2 + tt;
                if (tap < 9) {
                    const int ch = dg * 9 + tap;
                    float oy = offb[(size_t)(2*ch    ) * HWSZ + pixoff];
                    float ox = offb[(size_t)(2*ch + 1) * HWSZ + pixoff];
                    float mk = offb[(size_t)(288 + ch) * HWSZ + pixoff];
                    float ys = (float)py + (float)(tap / 3 - 1) + oy;
                    float xs = (float)px + (float)(tap % 3 - 1) + ox;
                    float y0f = floorf(ys), x0f = floorf(xs);
                    float wy = ys - y0f,    wx = xs - x0f;
                    int y0 = (int)y0f, x0i = (int)x0f;
                    int y1 = y0 + 1,   x1  = x0i + 1;
                    float fy0 = (y0  >= 0 && y0  < HH) ? 1.0f : 0.0f;
                    float fy1 = (y1  >= 0 && y1  < HH) ? 1.0f : 0.0f;
                    float fx0 = (x0i >= 0 && x0i < WW) ? 1.0f : 0.0f;
                    float fx1 = (x1  >= 0 && x1  < WW) ? 1.0f : 0.0f;
                    int yc0 = min(max(y0, 0), HH-1), yc1 = min(max(y1, 0), HH-1);
                    int xc0 = min(max(x0i,0), WW-1), xc1 = min(max(x1, 0), WW-1);
                    // fold validity + mask into the 4 bilinear weights
                    float w00 = (1.0f-wy)*(1.0f-wx)*fy0*fx0*mk;
                    float w01 = (1.0f-wy)*wx       *fy0*fx1*mk;
                    float w10 = wy       *(1.0f-wx)*fy1*fx0*mk;
                    float w11 = wy       *wx       *fy1*fx1*mk;
                    const float* p00 = xTb + ((size_t)(yc0*WW + xc0) * 64 + dg*4);
                    const float* p01 = xTb + ((size_t)(yc0*WW + xc1) * 64 + dg*4);
                    const float* p10 = xTb + ((size_t)(yc1*WW + xc0) * 64 + dg*4);
                    const float* p11 = xTb + ((size_t)(yc1*WW + xc1) * 64 + dg*4);
                    float4 c00 = *(const float4*)p00;
                    float4 c01 = *(const float4*)p01;
                    float4 c10 = *(const float4*)p10;
                    float4 c11 = *(const float4*)p11;
                    sv[tt*4+0] = c00.x*w00 + c01.x*w01 + c10.x*w10 + c11.x*w11;
                    sv[tt*4+1] = c00.y*w00 + c01.y*w01 + c10.y*w10 + c11.y*w11;
                    sv[tt*4+2] = c00.z*w00 + c01.z*w01 + c10.z*w10 + c11.z*w11;
                    sv[tt*4+3] = c00.w*w00 + c01.w*w01 + c10.w*w10 + c11.w*w11;
                }
            }
            bf16x8 h, l;
#pragma unroll
            for (int j = 0; j < 8; ++j) {
                bf16_t hh, ll; split_bf16(sv[j], hh, ll);
                h[j] = hh; l[j] = ll;
            }
            Ah[ks] = h; Al[ks] = l;
        }
        const bf16_t* bbase = Bp + (size_t)(dg * 3) * 64 * 2 * 16;
#pragma unroll
        for (int ks = 0; ks < 3; ++ks) {
#pragma unroll
            for (int nt = 0; nt < 2; ++nt) {
                const bf16_t* bp = bbase + ((size_t)(ks*64 + nt*32 + m) * 2) * 16 + klane*8;
                bf16x8 Bh = *(const bf16x8*)bp;
                bf16x8 Bl = *(const bf16x8*)(bp + 16);
                acc[nt] = __builtin_amdgcn_mfma_f32_32x32x16_bf16(Ah[ks], Bh, acc[nt], 0,0,0);
                acc[nt] = __builtin_amdgcn_mfma_f32_32x32x16_bf16(Al[ks], Bh, acc[nt], 0,0,0);
                acc[nt] = __builtin_amdgcn_mfma_f32_32x32x16_bf16(Ah[ks], Bl, acc[nt], 0,0,0);
            }
        }
    }

#pragma unroll
    for (int nt = 0; nt < 2; ++nt) {
        const int oc = nt * 32 + m;
        const float bv = bias[oc];
#pragma unroll
        for (int r = 0; r < 16; ++r) {
            const int row = (r & 3) + 8 * (r >> 2) + 4 * klane;
            const int gy = ty0 + wv * 2 + (row >> 4);
            const int gx = tx0 + (row & 15);
            out[((size_t)(b*64 + oc) << 14) + gy * WW + gx] = acc[nt][r] + bv;
        }
    }
}

// ---------------------------------------------------------------------------
extern "C" void kernel_launch(void* const* d_in, const int* in_sizes, int n_in,
                              void* d_out, int out_size, void* d_ws, size_t ws_size,
                              hipStream_t stream)
{
    const float* x    = (const float*)d_in[0];
    const float* xfw  = (const float*)d_in[1];
    const float* xc   = (const float*)d_in[2];
    const float* flow = (const float*)d_in[3];
    const float* w1 = (const float*)d_in[4];  const float* b1 = (const float*)d_in[5];
    const float* w2 = (const float*)d_in[6];  const float* b2 = (const float*)d_in[7];
    const float* w3 = (const float*)d_in[8];  const float* b3 = (const float*)d_in[9];
    const float* w4 = (const float*)d_in[10]; const float* b4 = (const float*)d_in[11];
    const float* dw = (const float*)d_in[12]; const float* db = (const float*)d_in[13];

    // workspace: A0 (41.9 MB) aliases off4 region (dead after conv1);
    // xT (16.78 MB fp32) aliases h2p (dead after conv3).
    char* wsb = (char*)d_ws;
    const size_t off4_bytes = (size_t)BB * 432 * HWSZ * 4;
    bf16_t* A0   = (bf16_t*)wsb;
    float*  off4 = (float*)wsb;
    char* p = wsb + off4_bytes;
    bf16_t* h1p = (bf16_t*)p;  p += (size_t)BB * HWSZ * 2 * 64 * 2;
    bf16_t* h2p = (bf16_t*)p;  float* xT = (float*)h2p;
                               p += (size_t)BB * HWSZ * 2 * 64 * 2;
    bf16_t* wp1 = (bf16_t*)p;  p += (size_t)9 * 64  * 2 * 160 * 2;
    bf16_t* wp2 = (bf16_t*)p;  p += (size_t)9 * 64  * 2 * 64  * 2;
    bf16_t* wp3 = (bf16_t*)p;  p += (size_t)9 * 64  * 2 * 64  * 2;
    bf16_t* wp4 = (bf16_t*)p;  p += (size_t)9 * 448 * 2 * 64  * 2;
    bf16_t* Bp  = (bf16_t*)p;  p += (size_t)16 * 3 * 64 * 2 * 16 * 2;

    pack_w_k<<<(9*64*160  + 255)/256, 256, 0, stream>>>(w1, wp1, 64, 130, 64, 160);
    pack_w_k<<<(9*64*64   + 255)/256, 256, 0, stream>>>(w2, wp2, 64, 64, 64, 64);
    pack_w_k<<<(9*64*64   + 255)/256, 256, 0, stream>>>(w3, wp3, 64, 64, 64, 64);
    pack_w_k<<<(9*448*64  + 255)/256, 256, 0, stream>>>(w4, wp4, 432, 64, 448, 64);
    pack_dw_k<<<(16*48*64 + 255)/256, 256, 0, stream>>>(dw, Bp);
    pack_a0_k<<<(BB*HWSZ*160 + 255)/256, 256, 0, stream>>>(xfw, xc, flow, A0);

    conv_mfma_k<160,0><<<dim3(64, BB, 1), 256, 0, stream>>>(A0,  wp1, b1, h1p, 64,  64,  nullptr);
    conv_mfma_k<64, 0><<<dim3(64, BB, 1), 256, 0, stream>>>(h1p, wp2, b2, h2p, 64,  64,  nullptr);
    conv_mfma_k<64, 0><<<dim3(64, BB, 1), 256, 0, stream>>>(h2p, wp3, b3, h1p, 64,  64,  nullptr);
    // xT overwrites h2p (dead after conv3)
    pack_xt_k<<<BB * HWSZ / 64, 256, 0, stream>>>(x, xT);
    conv_mfma_k<64, 1><<<dim3(64, BB, 7), 256, 0, stream>>>(h1p, wp4, b4, off4, 448, 432, flow);

    dcn_mfma_k<<<dim3(8, 16, BB), 256, 0, stream>>>(xT, off4, Bp, db, (float*)d_out);
}